// Round 5
// baseline (296.832 us; speedup 1.0000x reference)
//
#include <hip/hip_runtime.h>

#define TT 512
#define HH 32

typedef _Float16 half2_t __attribute__((ext_vector_type(2)));

__device__ __forceinline__ float fast_exp2(float v) { return __builtin_amdgcn_exp2f(v); }
__device__ __forceinline__ float fast_rcp(float v)  { return __builtin_amdgcn_rcpf(v); }

__device__ __forceinline__ float sigmoid_f(float v) {
    return fast_rcp(1.0f + fast_exp2(-1.442695040888963f * v));
}

__device__ __forceinline__ half2_t u2h(unsigned int u) {
    return __builtin_bit_cast(half2_t, u);
}

__global__ __launch_bounds__(64, 4) void lstm_fused_kernel(
    const float* __restrict__ x,     // [B, T, 1]
    const float* __restrict__ wih,   // [128, 1]
    const float* __restrict__ whh,   // [128, 32]
    const float* __restrict__ bih,   // [128]
    const float* __restrict__ bhh,   // [128]
    const float* __restrict__ fc1w,  // [16, 32]
    const float* __restrict__ fc1b,  // [16]
    const float* __restrict__ fc2w,  // [1, 16]
    const float* __restrict__ fc2b,  // [1]
    float* __restrict__ out)         // [B, 1]
{
    __shared__ float    lds_x[TT];
    __shared__ _Float16 lds_h[64];

    const int lane = threadIdx.x;   // block = one wave
    const int b = blockIdx.x;

    // ---- stage x[b][0..511] into LDS (coalesced float4) ----
    {
        const float4* xv = reinterpret_cast<const float4*>(x + (size_t)b * TT);
        float4* lv = reinterpret_cast<float4*>(&lds_x[0]);
        lv[lane]      = xv[lane];
        lv[lane + 64] = xv[lane + 64];
    }

    const int g0 = lane;
    const int g1 = lane + 64;

    // load W_hh rows, convert to packed fp16 words; pin in VGPRs with opaque asm
    unsigned int w0u[16], w1u[16];
    {
        const float4* r0 = reinterpret_cast<const float4*>(whh + g0 * HH);
        const float4* r1 = reinterpret_cast<const float4*>(whh + g1 * HH);
#pragma unroll
        for (int k4 = 0; k4 < 8; ++k4) {
            float4 a = r0[k4];
            half2_t p0; p0[0] = (_Float16)a.x; p0[1] = (_Float16)a.y;
            half2_t p1; p1[0] = (_Float16)a.z; p1[1] = (_Float16)a.w;
            w0u[k4 * 2 + 0] = __builtin_bit_cast(unsigned int, p0);
            w0u[k4 * 2 + 1] = __builtin_bit_cast(unsigned int, p1);
            float4 bb = r1[k4];
            half2_t q0h; q0h[0] = (_Float16)bb.x; q0h[1] = (_Float16)bb.y;
            half2_t q1h; q1h[0] = (_Float16)bb.z; q1h[1] = (_Float16)bb.w;
            w1u[k4 * 2 + 0] = __builtin_bit_cast(unsigned int, q0h);
            w1u[k4 * 2 + 1] = __builtin_bit_cast(unsigned int, q1h);
        }
    }
#pragma unroll
    for (int k = 0; k < 16; ++k) {
        asm volatile("" : "+v"(w0u[k]));
        asm volatile("" : "+v"(w1u[k]));
    }

    const float wi0   = wih[g0];
    const float wi1   = wih[g1];
    const float bias0 = bih[g0] + bhh[g0];
    const float bias1 = bih[g1] + bhh[g1];

    const bool lo = (lane < HH);
    const float kk = lo ? -2.885390081777927f : -1.442695040888963f;
    const float sc = lo ? 2.0f : 1.0f;
    const float ad = lo ? -1.0f : 0.0f;

    lds_h[lane] = (_Float16)0.0f;
    float c = 0.0f;

    __syncthreads();

#pragma unroll 1
    for (int t0 = 0; t0 < TT; t0 += 4) {
        const float4 xq = *reinterpret_cast<const float4*>(&lds_x[t0]);
#pragma unroll
        for (int u = 0; u < 4; ++u) {
            const float xt = (u == 0) ? xq.x : (u == 1) ? xq.y : (u == 2) ? xq.z : xq.w;

            // broadcast-read packed h (uniform addresses -> conflict-free)
            unsigned int hh[16];
            {
                const uint4* hp = reinterpret_cast<const uint4*>(&lds_h[0]);
                uint4 q0 = hp[0];
                uint4 q1 = hp[1];
                uint4 q2 = hp[2];
                uint4 q3 = hp[3];
                hh[0]  = q0.x; hh[1]  = q0.y; hh[2]  = q0.z; hh[3]  = q0.w;
                hh[4]  = q1.x; hh[5]  = q1.y; hh[6]  = q1.z; hh[7]  = q1.w;
                hh[8]  = q2.x; hh[9]  = q2.y; hh[10] = q2.z; hh[11] = q2.w;
                hh[12] = q3.x; hh[13] = q3.y; hh[14] = q3.z; hh[15] = q3.w;
            }

            // two independent 8-deep chains per gate pair
            float acc0a = __builtin_fmaf(xt, wi0, bias0);
            float acc1a = __builtin_fmaf(xt, wi1, bias1);
            float acc0b = 0.0f;
            float acc1b = 0.0f;
#pragma unroll
            for (int k = 0; k < 8; ++k) {
                acc0a = __builtin_amdgcn_fdot2(u2h(hh[k]), u2h(w0u[k]), acc0a, false);
                acc1a = __builtin_amdgcn_fdot2(u2h(hh[k]), u2h(w1u[k]), acc1a, false);
            }
#pragma unroll
            for (int k = 8; k < 16; ++k) {
                acc0b = __builtin_amdgcn_fdot2(u2h(hh[k]), u2h(w0u[k]), acc0b, false);
                acc1b = __builtin_amdgcn_fdot2(u2h(hh[k]), u2h(w1u[k]), acc1b, false);
            }
            const float acc0 = acc0a + acc0b;
            const float acc1 = acc1a + acc1b;

            // activations
            const float a0 = sigmoid_f(acc0);
            const float a1 = __builtin_fmaf(sc, fast_rcp(1.0f + fast_exp2(kk * acc1)), ad);

            // exchange halves: lane j <-> lane j+32
            const float p0 = __shfl_xor(a0, 32);
            const float p1 = __shfl_xor(a1, 32);
            const float i_ = lo ? a0 : p0;
            const float f_ = lo ? p0 : a0;
            const float g_ = lo ? a1 : p1;
            const float o_ = lo ? p1 : a1;

            c = __builtin_fmaf(f_, c, i_ * g_);
            // h = o*tanh(c)
            const float e  = fast_exp2(-2.885390081777927f * c);
            const float hn = __builtin_fmaf(2.0f * o_, fast_rcp(1.0f + e), -o_);

            lds_h[lane] = (_Float16)hn;
        }
    }

    // ---- final h (fp32) from LDS (written on last iteration) ----
    float hfin[HH];
    {
        const uint4* hp = reinterpret_cast<const uint4*>(&lds_h[0]);
        uint4 q0 = hp[0];
        uint4 q1 = hp[1];
        uint4 q2 = hp[2];
        uint4 q3 = hp[3];
        unsigned int w[16] = {q0.x,q0.y,q0.z,q0.w, q1.x,q1.y,q1.z,q1.w,
                              q2.x,q2.y,q2.z,q2.w, q3.x,q3.y,q3.z,q3.w};
#pragma unroll
        for (int k = 0; k < 16; ++k) {
            half2_t h2 = u2h(w[k]);
            hfin[2 * k + 0] = (float)h2[0];
            hfin[2 * k + 1] = (float)h2[1];
        }
    }

    // ---- MLP head: z = relu(h@fc1w.T + fc1b); out = z@fc2w.T + fc2b ----
    float val = 0.0f;
    if (lane < 16) {
        float acc = fc1b[lane];
#pragma unroll
        for (int j = 0; j < HH; ++j) acc = __builtin_fmaf(hfin[j], fc1w[lane * HH + j], acc);
        val = fmaxf(acc, 0.0f) * fc2w[lane];
    }
#pragma unroll
    for (int off = 8; off; off >>= 1) val += __shfl_down(val, off);
    if (lane == 0) out[b] = val + fc2b[0];
}

extern "C" void kernel_launch(void* const* d_in, const int* in_sizes, int n_in,
                              void* d_out, int out_size, void* d_ws, size_t ws_size,
                              hipStream_t stream) {
    const float* x    = (const float*)d_in[0];
    const float* wih  = (const float*)d_in[1];
    const float* whh  = (const float*)d_in[2];
    const float* bih  = (const float*)d_in[3];
    const float* bhh  = (const float*)d_in[4];
    const float* fc1w = (const float*)d_in[5];
    const float* fc1b = (const float*)d_in[6];
    const float* fc2w = (const float*)d_in[7];
    const float* fc2b = (const float*)d_in[8];
    float* out = (float*)d_out;

    const int B = out_size;            // 4096
    dim3 grid(B), block(64);
    hipLaunchKernelGGL(lstm_fused_kernel, grid, block, 0, stream,
                       x, wih, whh, bih, bhh, fc1w, fc1b, fc2w, fc2b, out);
}